// Round 7
// baseline (129.220 us; speedup 1.0000x reference)
//
#include <hip/hip_runtime.h>
#include <math.h>

#define NN    4096
#define KK    20
#define SUBS  16
#define PPB   32
#define BLK   (PPB*SUBS)        // 512 threads, 8 waves
#define TILE  512
#define NT    (NN/TILE)         // 8 tiles
#define CHUNK (TILE/SUBS)       // 32 points per sub per tile
#define M     3                 // per-sub short-list (16*3=48 >= 21)
#define CAP   48                // per-point candidate capacity
#define CROW  49                // padded row stride
#define BPB   (NN/PPB)          // 128 blocks per batch

__global__ __launch_bounds__(BLK, 2)
void edgeconv_kernel(const float* __restrict__ x,
                     const float* __restrict__ W,
                     const float* __restrict__ bias,
                     float* __restrict__ out) {
  // (x, y, z, |x|^2) per point; 512B-aligned so chunk bases have bits 4-6 = 0
  __shared__ __align__(512) float tiles[2][TILE * 4];  // 16 KB double-buffered
  __shared__ float smin[PPB][CROW];                    // top-3 lists; reused as jkeep
  __shared__ float dcand[PPB][CROW];
  __shared__ int   jcand[PPB][CROW];
  __shared__ float taub[PPB];
  __shared__ int   pc[PPB];
  __shared__ int   pk[PPB];

  const int tid  = threadIdx.x;
  const int g    = tid >> 4;          // point group 0..31
  const int s    = tid & 15;          // sub-scanner 0..15
  const int sx   = s & 7;
  const int bb   = blockIdx.x / BPB;
  const int blk  = blockIdx.x % BPB;
  const int base = bb * NN;
  const int myp  = blk * PPB + g;

  const float mx = x[(size_t)(base + myp) * 3 + 0];
  const float my = x[(size_t)(base + myp) * 3 + 1];
  const float mz = x[(size_t)(base + myp) * 3 + 2];
  // d' = |xj|^2 - 2*xi.xj = dist2 - |xi|^2 (order-preserving; self = strict min)
  const float nx = -2.f * mx, ny = -2.f * my, nz = -2.f * mz;

  // ---- stage tile 0: one point per thread ----------------------------------
  {
    const float* p = x + (size_t)(base + tid) * 3;
    const float a = p[0], b2 = p[1], c = p[2];
    *(float4*)&tiles[0][tid << 2] =
        make_float4(a, b2, c, fmaf(c, c, fmaf(b2, b2, a * a)));
  }
  __syncthreads();

  float nd[M];                                         // descending: nd[0]=max
  #pragma unroll
  for (int i = 0; i < M; ++i) nd[i] = INFINITY;

  // byte offset of this sub's chunk within a tile buffer, +XOR rotation key:
  // chunk base s*512 (bits 4-6 zero), key (s&7)*16 -> read = boff ^ (i<<4).
  // Start banks tile 2-way across the 16 subs (the b128 BW floor).
  const int boff = (s << 9) | (sx << 4);

  // ---------------- Phase A: per-sub top-3 d' values (self rides along) ------
  {
    int cur = 0;
    for (int t = 0; t < NT; ++t) {
      float pa, pb, pcf;
      const bool more = (t + 1 < NT);
      if (more) {
        const float* p = x + (size_t)(base + (t + 1) * TILE + tid) * 3;
        pa = p[0]; pb = p[1]; pcf = p[2];
      }
      const char* tf = (const char*)&tiles[cur][0];
      #pragma unroll
      for (int i = 0; i < CHUNK; ++i) {
        const float4 v = *(const float4*)(tf + (boff ^ (i << 4)));
        const float d = fmaf(nx, v.x, fmaf(ny, v.y, fmaf(nz, v.z, v.w)));
        nd[0] = __builtin_amdgcn_fmed3f(nd[0], nd[1], d);   // sorted insert
        nd[1] = __builtin_amdgcn_fmed3f(nd[1], nd[2], d);
        nd[2] = fminf(nd[2], d);
      }
      if (more) {
        *(float4*)&tiles[cur ^ 1][tid << 2] =
            make_float4(pa, pb, pcf, fmaf(pcf, pcf, fmaf(pb, pb, pa * pa)));
        __syncthreads();
        cur ^= 1;
      }
    }
  }
  #pragma unroll
  for (int i = 0; i < M; ++i) smin[g][s * M + i] = nd[M - 1 - i];  // ascending
  __syncthreads();

  // prefetch tile 0 for Phase B (store after merge) + zero counters
  float pa0, pb0, pc0;
  {
    const float* p = x + (size_t)(base + tid) * 3;
    pa0 = p[0]; pb0 = p[1]; pc0 = p[2];
  }
  if (tid < PPB) { pc[tid] = 0; pk[tid] = 0; }

  // ---- Merge: tau_hat = 21st smallest of the 48-union (>= true tau; exactly
  //      one self value in the union). Parallel rank-select. ------------------
  {
    const float* L = &smin[g][0];
    const float v0 = L[3 * s], v1 = L[3 * s + 1], v2 = L[3 * s + 2];
    int lt0 = 0, le0 = 0, lt1 = 0, le1 = 0, lt2 = 0, le2 = 0;
    #pragma unroll 4
    for (int j = 0; j < SUBS * M; ++j) {
      const float u = L[j];
      lt0 += (u <  v0); le0 += (u <= v0);
      lt1 += (u <  v1); le1 += (u <= v1);
      lt2 += (u <  v2); le2 += (u <= v2);
    }
    if (lt0 <= KK && KK < le0) taub[g] = v0;   // benign same-value race
    if (lt1 <= KK && KK < le1) taub[g] = v1;
    if (lt2 <= KK && KK < le2) taub[g] = v2;
  }
  {
    *(float4*)&tiles[0][tid << 2] =
        make_float4(pa0, pb0, pc0, fmaf(pc0, pc0, fmaf(pb0, pb0, pa0 * pa0)));
  }
  __syncthreads();   // tile 0 staged, counters zeroed, taub written
  const float tau = taub[g];

  // ---------------- Phase B: collect candidates d' <= tau (self included) ----
  {
    int cur = 0;
    for (int t = 0; t < NT; ++t) {
      float pa, pb, pcf;
      const bool more = (t + 1 < NT);
      if (more) {
        const float* p = x + (size_t)(base + (t + 1) * TILE + tid) * 3;
        pa = p[0]; pb = p[1]; pcf = p[2];
      }
      const char* tf = (const char*)&tiles[cur][0];
      const int jb = t * TILE + (s << 5);
      #pragma unroll
      for (int i = 0; i < CHUNK; ++i) {
        const float4 v = *(const float4*)(tf + (boff ^ (i << 4)));
        const float d = fmaf(nx, v.x, fmaf(ny, v.y, fmaf(nz, v.z, v.w)));
        if (d <= tau) {
          int w = atomicAdd(&pc[g], 1);
          if (w < CAP) { dcand[g][w] = d; jcand[g][w] = jb + (i ^ sx); }
        }
      }
      if (more) {
        *(float4*)&tiles[cur ^ 1][tid << 2] =
            make_float4(pa, pb, pcf, fmaf(pcf, pcf, fmaf(pb, pb, pa * pa)));
        __syncthreads();
        cur ^= 1;
      }
    }
  }
  __syncthreads();

  // ---- Rank + compact: keep j != self with lex-rank(d, j) <= 20 (exactly 20;
  //      matches top_k's low-index tie-break; kept SET is deterministic) ------
  int (*jkeep)[CROW] = (int(*)[CROW])smin;             // smin dead after merge
  {
    const int n0 = pc[g];
    const int n = n0 < CAP ? n0 : CAP;
    for (int k = s; k < n; k += SUBS) {
      const float dk = dcand[g][k];
      const int   jk = jcand[g][k];
      int rank = 0;
      for (int k2 = 0; k2 < n; ++k2) {
        const float d2 = dcand[g][k2];
        const int   j2 = jcand[g][k2];
        rank += (d2 < dk || (d2 == dk && j2 < jk)) ? 1 : 0;
      }
      if (jk != myp && rank <= KK) {
        const int w = atomicAdd(&pk[g], 1);
        jkeep[g][w] = jk;
      }
    }
  }
  __syncthreads();

  // ---------------- Feature phase: lane = channel; h = xj.w345 + const_i -----
  const int wv   = tid >> 6;           // wave 0..7
  const int lane = tid & 63;
  const float w3 = W[3*64+lane], w4 = W[4*64+lane], w5 = W[5*64+lane];
  const float c0 = W[0*64+lane] - w3;
  const float c1 = W[1*64+lane] - w4;
  const float c2 = W[2*64+lane] - w5;
  const float bo = bias[lane];

  for (int pi = 0; pi < PPB / 8; ++pi) {       // 4 points per wave
    const int p   = wv * (PPB / 8) + pi;
    const int pid = blk * PPB + p;
    const float* xi = x + (size_t)(base + pid) * 3;
    const float ci = fmaf(xi[0], c0, fmaf(xi[1], c1, fmaf(xi[2], c2, bo)));
    float hmax = -INFINITY;
    #pragma unroll 5
    for (int k = 0; k < KK; ++k) {             // exactly 20, wave-uniform
      const int j = jkeep[p][k];
      const float* xp = x + (size_t)(base + j) * 3;
      hmax = fmaxf(hmax, fmaf(xp[0], w3, fmaf(xp[1], w4, fmaf(xp[2], w5, ci))));
    }
    out[(size_t)(base + pid) * 64 + lane] = fmaxf(hmax, 0.0f);
  }
}

extern "C" void kernel_launch(void* const* d_in, const int* in_sizes, int n_in,
                              void* d_out, int out_size, void* d_ws, size_t ws_size,
                              hipStream_t stream) {
  const float* x  = (const float*)d_in[0];
  // d_in[1] = batch (implicit: i / N) — unused
  const float* W  = (const float*)d_in[2];
  const float* b  = (const float*)d_in[3];
  float* out = (float*)d_out;

  dim3 grid(8 * BPB);   // 1024 blocks: 8 batches x 128 point-groups
  dim3 block(BLK);
  hipLaunchKernelGGL(edgeconv_kernel, grid, block, 0, stream, x, W, b, out);
}

// Round 8
// 97.912 us; speedup vs baseline: 1.3198x; 1.3198x over previous
//
#include <hip/hip_runtime.h>
#include <math.h>

#define NN    4096
#define KK    20
#define QQ    4                 // query points per lane (per wave)
#define PPB   32                // 8 waves x 4 queries
#define BLK   512               // 8 waves
#define TILE  512
#define NT    (NN/TILE)         // 8 tiles
#define IPT   (TILE/64)         // 8 iterations per tile per lane
#define CAP   56                // per-point candidate capacity
#define CROW  57                // candidate row stride (float2)
#define BPB   (NN/PPB)          // 128 blocks per batch

__device__ __forceinline__ unsigned fkey(float f) {  // monotone float->uint
  unsigned u = __float_as_uint(f);
  return u ^ ((unsigned)((int)u >> 31) | 0x80000000u);
}
__device__ __forceinline__ float fkey_inv(unsigned k) {
  unsigned u = (k & 0x80000000u) ? (k ^ 0x80000000u) : ~k;
  return __uint_as_float(u);
}

__global__ __launch_bounds__(BLK, 2)
void edgeconv_kernel(const float* __restrict__ x,
                     const float* __restrict__ W,
                     const float* __restrict__ bias,
                     float* __restrict__ out) {
  __shared__ __align__(512) float tiles[2][TILE * 4];   // (x,y,z,|x|^2), 16 KB
  __shared__ float2 cand[PPB][CROW];                    // 14.25 KB (d, j-bits)
  __shared__ int    jkeep[PPB][21];                     // 2.6 KB
  __shared__ int    pc[PPB];
  __shared__ int    pk[PPB];

  const int tid  = threadIdx.x;
  const int lane = tid & 63;
  const int w    = tid >> 6;
  const int bb   = blockIdx.x / BPB;
  const int blk  = blockIdx.x % BPB;
  const int base = bb * NN;
  const int g0   = w * QQ;                 // wave's first point group
  const int myp0 = blk * PPB + g0;

  // premultiplied query coeffs: d' = |xj|^2 - 2*xi.xj (order-preserving/point)
  float nx[QQ], ny[QQ], nz[QQ];
  #pragma unroll
  for (int q = 0; q < QQ; ++q) {
    const float* p = x + (size_t)(base + myp0 + q) * 3;
    nx[q] = -2.f * p[0]; ny[q] = -2.f * p[1]; nz[q] = -2.f * p[2];
  }

  // stage tile 0: one point per thread; (x,y,z,sq) float4
  {
    const float* p = x + (size_t)(base + tid) * 3;
    const float a = p[0], b = p[1], c = p[2];
    *(float4*)&tiles[0][tid << 2] =
        make_float4(a, b, c, fmaf(c, c, fmaf(b, b, a * a)));
  }
  if (tid < PPB) { pc[tid] = 0; pk[tid] = 0; }
  __syncthreads();

  // ---------------- Phase A: per-(lane,query) min over j = lane (mod 64) -----
  float m[QQ];
  #pragma unroll
  for (int q = 0; q < QQ; ++q) m[q] = INFINITY;
  {
    int cur = 0;
    for (int t = 0; t < NT; ++t) {
      float pa, pb, pcf;
      const bool more = (t + 1 < NT);
      if (more) {
        const float* p = x + (size_t)(base + (t + 1) * TILE + tid) * 3;
        pa = p[0]; pb = p[1]; pcf = p[2];
      }
      const float* tp = &tiles[cur][lane << 2];
      #pragma unroll
      for (int i = 0; i < IPT; ++i) {       // contiguous b128, imm offset i*1024
        const float4 v = *(const float4*)(tp + i * 256);
        #pragma unroll
        for (int q = 0; q < QQ; ++q) {
          const float d = fmaf(nx[q], v.x, fmaf(ny[q], v.y, fmaf(nz[q], v.z, v.w)));
          m[q] = fminf(m[q], d);
        }
      }
      if (more) {
        *(float4*)&tiles[cur ^ 1][tid << 2] =
            make_float4(pa, pb, pcf, fmaf(pcf, pcf, fmaf(pb, pb, pa * pa)));
        __syncthreads();
        cur ^= 1;
      }
    }
  }

  // prefetch tile-0 regs for Phase B (hide under tau computation)
  float pa0, pb0, pc0;
  { const float* p = x + (size_t)(base + tid) * 3; pa0 = p[0]; pb0 = p[1]; pc0 = p[2]; }

  // ---- tau_q = exact 21st smallest of the 64 lane-minima (>= true tau;
  //      exactly one self value, the strict minimum, is in the set).
  //      Wave-ballot radix bisection: 32 iters, uniform control. -------------
  unsigned key[QQ], lo[QQ], hi[QQ];
  #pragma unroll
  for (int q = 0; q < QQ; ++q) { key[q] = fkey(m[q]); lo[q] = 0u; hi[q] = 0xFFFFFFFFu; }
  for (int b = 0; b < 32; ++b) {
    #pragma unroll
    for (int q = 0; q < QQ; ++q) {
      const unsigned mid = lo[q] + ((hi[q] - lo[q]) >> 1);
      const unsigned long long bal = __ballot(key[q] <= mid);
      if (__popcll(bal) > KK) hi[q] = mid; else lo[q] = mid + 1;
    }
  }
  float tau[QQ];
  #pragma unroll
  for (int q = 0; q < QQ; ++q) tau[q] = fkey_inv(lo[q]);

  *(float4*)&tiles[0][tid << 2] =
      make_float4(pa0, pb0, pc0, fmaf(pc0, pc0, fmaf(pb0, pb0, pa0 * pa0)));
  __syncthreads();   // tile 0 restaged; counters zeroed earlier

  // ---------------- Phase B: collect candidates d' <= tau_q (self included) --
  {
    int cur = 0;
    for (int t = 0; t < NT; ++t) {
      float pa, pb, pcf;
      const bool more = (t + 1 < NT);
      if (more) {
        const float* p = x + (size_t)(base + (t + 1) * TILE + tid) * 3;
        pa = p[0]; pb = p[1]; pcf = p[2];
      }
      const float* tp = &tiles[cur][lane << 2];
      #pragma unroll
      for (int i = 0; i < IPT; ++i) {
        const float4 v = *(const float4*)(tp + i * 256);
        const int j = t * TILE + i * 64 + lane;
        #pragma unroll
        for (int q = 0; q < QQ; ++q) {
          const float d = fmaf(nx[q], v.x, fmaf(ny[q], v.y, fmaf(nz[q], v.z, v.w)));
          if (d <= tau[q]) {
            const int wp = atomicAdd(&pc[g0 + q], 1);
            if (wp < CAP) cand[g0 + q][wp] = make_float2(d, __int_as_float(j));
          }
        }
      }
      if (more) {
        *(float4*)&tiles[cur ^ 1][tid << 2] =
            make_float4(pa, pb, pcf, fmaf(pcf, pcf, fmaf(pb, pb, pa * pa)));
        __syncthreads();
        cur ^= 1;
      }
    }
  }
  __syncthreads();

  // ---- Rank + compact: keep j != self with lex-rank(d, j) <= 20 (exactly 20;
  //      matches top_k's low-index tie-break; kept SET deterministic) ---------
  {
    const int g   = tid >> 4;
    const int k0  = tid & 15;
    const int myp = blk * PPB + g;
    const int n0  = pc[g];
    const int n   = n0 < CAP ? n0 : CAP;
    for (int k = k0; k < n; k += 16) {
      const float2 ck = cand[g][k];
      const float dk = ck.x; const int jk = __float_as_int(ck.y);
      int rank = 0;
      for (int k2 = 0; k2 < n; ++k2) {
        const float2 c2 = cand[g][k2];
        rank += (c2.x < dk || (c2.x == dk && __float_as_int(c2.y) < jk)) ? 1 : 0;
      }
      if (jk != myp && rank <= KK) jkeep[g][atomicAdd(&pk[g], 1)] = jk;
    }
  }
  __syncthreads();

  // ---------------- Feature phase: lane = channel; h = xj.w345 + const_i -----
  const float w3 = W[3*64+lane], w4 = W[4*64+lane], w5 = W[5*64+lane];
  const float c0 = W[0*64+lane] - w3;
  const float c1 = W[1*64+lane] - w4;
  const float c2 = W[2*64+lane] - w5;
  const float bo = bias[lane];

  for (int pi = 0; pi < QQ; ++pi) {          // wave's own 4 points
    const int p   = g0 + pi;
    const int pid = blk * PPB + p;
    const float* xi = x + (size_t)(base + pid) * 3;
    const float ci = fmaf(xi[0], c0, fmaf(xi[1], c1, fmaf(xi[2], c2, bo)));
    float hmax = -INFINITY;
    #pragma unroll 5
    for (int k = 0; k < KK; ++k) {           // exactly 20, wave-uniform
      const int j = jkeep[p][k];
      const float* xp = x + (size_t)(base + j) * 3;
      hmax = fmaxf(hmax, fmaf(xp[0], w3, fmaf(xp[1], w4, fmaf(xp[2], w5, ci))));
    }
    out[(size_t)(base + pid) * 64 + lane] = fmaxf(hmax, 0.0f);
  }
}

extern "C" void kernel_launch(void* const* d_in, const int* in_sizes, int n_in,
                              void* d_out, int out_size, void* d_ws, size_t ws_size,
                              hipStream_t stream) {
  const float* x  = (const float*)d_in[0];
  // d_in[1] = batch (implicit: i / N) — unused
  const float* W  = (const float*)d_in[2];
  const float* b  = (const float*)d_in[3];
  float* out = (float*)d_out;

  dim3 grid(8 * BPB);   // 1024 blocks: 8 batches x 128 point-groups
  dim3 block(BLK);
  hipLaunchKernelGGL(edgeconv_kernel, grid, block, 0, stream, x, W, b, out);
}